// Round 2
// baseline (237.515 us; speedup 1.0000x reference)
//
#include <hip/hip_runtime.h>
#include <cstddef>

#define SSM_N 64
#define SSM_H 256
#define SSM_B 8
#define SSM_L 1024
#define PADM  68   // row stride (floats) for 64x64 LDS matrices; 272B rows, 16B-aligned
#define PADC  68   // row stride for 32-row chain buffers (float4-aligned)

// One block per channel h. 256 threads = 4 waves; wave q owns output columns [16q,16q+16).
__global__ __launch_bounds__(256) void ssm_prep_kernel(
    const float* __restrict__ As, const float* __restrict__ Bsin,
    const float* __restrict__ Csin, const float* __restrict__ logsteps,
    float* __restrict__ Kout)
{
    __shared__ __align__(16) float B0[SSM_N * PADM];
    __shared__ __align__(16) float B1[SSM_N * PADM];
    __shared__ __align__(16) float CallL[32 * PADC];
    __shared__ __align__(16) float XallL[32 * PADC];
    __shared__ float pbuf[4 * 64];

    const int h    = blockIdx.x;
    const int tid  = threadIdx.x;
    const int lane = tid & 63;
    const int q    = tid >> 6;
    const int j0   = q * 16;

    const float step = expf(logsteps[h]);
    const float s    = 0.5f * step;

    // ---- 1. M = s*A: lane's row into 64 regs (all waves), staged in B1 (wave 0) ----
    float arow[64];
    {
        const float4* Ar = reinterpret_cast<const float4*>(As + (size_t)h * 4096 + lane * 64);
        #pragma unroll
        for (int r = 0; r < 16; ++r) {
            float4 v = Ar[r];
            arow[4*r+0] = s * v.x; arow[4*r+1] = s * v.y;
            arow[4*r+2] = s * v.z; arow[4*r+3] = s * v.w;
        }
        if (q == 0) {
            float4* wp = reinterpret_cast<float4*>(B1 + lane * PADM);
            #pragma unroll
            for (int r = 0; r < 16; ++r)
                wp[r] = make_float4(arow[4*r], arow[4*r+1], arow[4*r+2], arow[4*r+3]);
        }
    }
    __syncthreads();

    // ---- 2. Neumann Horner: B0 = M*M + M; then B0 = M*B0 + M  (B0 = S = M+M^2+M^3) ----
    // A-operand from regs; B-operand: wave-uniform float4 broadcasts. Wave q only
    // touches column slice [j0,j0+16) of B0 (all 64 rows) -> no inter-iter barrier.
    #pragma unroll 1
    for (int it = 0; it < 2; ++it) {
        const float* Bop = (it == 0) ? B1 : B0;
        float acc[16];
        #pragma unroll
        for (int jj = 0; jj < 16; ++jj) acc[jj] = arow[j0 + jj];   // the "+M" term
        #pragma unroll
        for (int k = 0; k < 64; ++k) {
            const float a = arow[k];
            const float4* bp = reinterpret_cast<const float4*>(Bop + k * PADM + j0);
            const float4 b0 = bp[0], b1v = bp[1], b2 = bp[2], b3 = bp[3];
            acc[0]  += a * b0.x;  acc[1]  += a * b0.y;  acc[2]  += a * b0.z;  acc[3]  += a * b0.w;
            acc[4]  += a * b1v.x; acc[5]  += a * b1v.y; acc[6]  += a * b1v.z; acc[7]  += a * b1v.w;
            acc[8]  += a * b2.x;  acc[9]  += a * b2.y;  acc[10] += a * b2.z;  acc[11] += a * b2.w;
            acc[12] += a * b3.x;  acc[13] += a * b3.y;  acc[14] += a * b3.z;  acc[15] += a * b3.w;
        }
        float4* wp = reinterpret_cast<float4*>(B0 + lane * PADM + j0);
        wp[0] = make_float4(acc[0],  acc[1],  acc[2],  acc[3]);
        wp[1] = make_float4(acc[4],  acc[5],  acc[6],  acc[7]);
        wp[2] = make_float4(acc[8],  acc[9],  acc[10], acc[11]);
        wp[3] = make_float4(acc[12], acc[13], acc[14], acc[15]);
    }
    __syncthreads();

    // ---- 3. stage b, Cs; build AbT = I + 2*S^T into B1 (M dead) ----
    if (q == 0)      pbuf[lane]  = Bsin[h * SSM_N + lane];
    else if (q == 1) CallL[lane] = Csin[h * SSM_N + lane];
    #pragma unroll
    for (int r = 0; r < 16; ++r) {
        int e = r * 256 + tid, i = e >> 6, j = e & 63;
        B1[j * PADM + i] = 2.f * B0[i * PADM + j] + ((i == j) ? 1.f : 0.f);
    }
    __syncthreads();

    // ---- 4. Bb = step*(b + S b) -> XallL row 0 (wave 0; reads own pbuf writes) ----
    if (q == 0) {
        float accb = 0.f;
        #pragma unroll
        for (int r = 0; r < 16; ++r) {
            const float4 sv = *reinterpret_cast<const float4*>(B0 + lane * PADM + 4 * r);
            accb += sv.x * pbuf[4*r] + sv.y * pbuf[4*r+1] + sv.z * pbuf[4*r+2] + sv.w * pbuf[4*r+3];
        }
        XallL[lane] = step * (pbuf[lane] + accb);
    }

    // ---- 5. c-chain: c_{j+1}[i] = sum_k c_j[k] * AbT[i][k]  (per-lane b128 row reads) ----
    #pragma unroll 1
    for (int j = 0; j < 31; ++j) {
        const float* crow = CallL + j * PADC;
        float pp = 0.f;
        #pragma unroll
        for (int r = 0; r < 4; ++r) {
            const float4 cc = *reinterpret_cast<const float4*>(crow + j0 + 4 * r);
            const float4 aa = *reinterpret_cast<const float4*>(B1 + lane * PADM + j0 + 4 * r);
            pp += cc.x * aa.x + cc.y * aa.y + cc.z * aa.z + cc.w * aa.w;
        }
        pbuf[q * 64 + lane] = pp;
        __syncthreads();
        if (q == 0)
            CallL[(j + 1) * PADC + lane] =
                pbuf[lane] + pbuf[64 + lane] + pbuf[128 + lane] + pbuf[192 + lane];
        __syncthreads();
    }

    // ---- 6. five squarings of AbT: B1 -> B0 -> B1 ... -> PT ends in B0 ----
    {
        float* src = B1;
        float* dst = B0;
        #pragma unroll 1
        for (int it = 0; it < 5; ++it) {
            #pragma unroll
            for (int r = 0; r < 16; ++r) {
                const float4 v = *reinterpret_cast<const float4*>(src + lane * PADM + 4 * r);
                arow[4*r] = v.x; arow[4*r+1] = v.y; arow[4*r+2] = v.z; arow[4*r+3] = v.w;
            }
            float acc[16];
            #pragma unroll
            for (int jj = 0; jj < 16; ++jj) acc[jj] = 0.f;
            #pragma unroll
            for (int k = 0; k < 64; ++k) {
                const float a = arow[k];
                const float4* bp = reinterpret_cast<const float4*>(src + k * PADM + j0);
                const float4 b0 = bp[0], b1v = bp[1], b2 = bp[2], b3 = bp[3];
                acc[0]  += a * b0.x;  acc[1]  += a * b0.y;  acc[2]  += a * b0.z;  acc[3]  += a * b0.w;
                acc[4]  += a * b1v.x; acc[5]  += a * b1v.y; acc[6]  += a * b1v.z; acc[7]  += a * b1v.w;
                acc[8]  += a * b2.x;  acc[9]  += a * b2.y;  acc[10] += a * b2.z;  acc[11] += a * b2.w;
                acc[12] += a * b3.x;  acc[13] += a * b3.y;  acc[14] += a * b3.z;  acc[15] += a * b3.w;
            }
            float4* wp = reinterpret_cast<float4*>(dst + lane * PADM + j0);
            wp[0] = make_float4(acc[0],  acc[1],  acc[2],  acc[3]);
            wp[1] = make_float4(acc[4],  acc[5],  acc[6],  acc[7]);
            wp[2] = make_float4(acc[8],  acc[9],  acc[10], acc[11]);
            wp[3] = make_float4(acc[12], acc[13], acc[14], acc[15]);
            __syncthreads();
            float* tmp = src; src = dst; dst = tmp;
        }
        // PT = (AbT)^32 now in B0.
    }

    // ---- 7. P := PT^T into B1 ----
    #pragma unroll
    for (int r = 0; r < 16; ++r) {
        int e = r * 256 + tid, i = e >> 6, jj = e & 63;
        B1[i * PADM + jj] = B0[jj * PADM + i];
    }
    __syncthreads();

    // ---- 8. x-chain: x_{m+1}[i] = sum_k P[i][k] x_m[k]  (per-lane b128 row reads) ----
    #pragma unroll 1
    for (int m = 0; m < 31; ++m) {
        const float* xrow = XallL + m * PADC;
        float pp = 0.f;
        #pragma unroll
        for (int r = 0; r < 4; ++r) {
            const float4 xx = *reinterpret_cast<const float4*>(xrow + j0 + 4 * r);
            const float4 aa = *reinterpret_cast<const float4*>(B1 + lane * PADM + j0 + 4 * r);
            pp += xx.x * aa.x + xx.y * aa.y + xx.z * aa.z + xx.w * aa.w;
        }
        pbuf[q * 64 + lane] = pp;
        __syncthreads();
        if (q == 0)
            XallL[(m + 1) * PADC + lane] =
                pbuf[lane] + pbuf[64 + lane] + pbuf[128 + lane] + pbuf[192 + lane];
        __syncthreads();
    }

    // ---- 9. K[32m + j][h] = dot(c_j, x_m) ----
    #pragma unroll
    for (int r = 0; r < 4; ++r) {
        int l = r * 256 + tid, mm = l >> 5, jj = l & 31;
        const float4* cr = reinterpret_cast<const float4*>(CallL + jj * PADC);
        const float4* xr = reinterpret_cast<const float4*>(XallL + mm * PADC);
        float sacc = 0.f;
        #pragma unroll
        for (int i = 0; i < 16; ++i) {
            const float4 c4 = cr[i], x4 = xr[i];
            sacc += c4.x * x4.x + c4.y * x4.y + c4.z * x4.z + c4.w * x4.w;
        }
        Kout[(size_t)l * SSM_H + h] = sacc;
    }
}

// Causal conv: y[b,l,h] = sum_d K[d,h]*u[b,l-d,h] + Ds[h]*u[b,l,h].
// thread = h (coalesced). 8-row tiles; block does tile pair (p, 127-p) -> uniform
// 129 chunks of 8 d-steps. 512 blocks = 2 blocks/CU. Next-chunk K/u prefetched
// before the FMA block so L2 latency hides under FMAs; window rotates once per 8 d.
__global__ __launch_bounds__(256) void ssm_conv_kernel(
    const float* __restrict__ U, const float* __restrict__ Kk,
    const float* __restrict__ Ds, float* __restrict__ Y)
{
    const int h = threadIdx.x;
    const int b = blockIdx.x & 7;
    const int p = blockIdx.x >> 3;
    const float dh = Ds[h];
    const float* Ub = U + (size_t)b * SSM_L * SSM_H + h;
    float* Yb = Y + (size_t)b * SSM_L * SSM_H + h;

    #pragma unroll
    for (int half = 0; half < 2; ++half) {
        const int t  = (half == 0) ? p : (127 - p);
        const int l0 = t << 3;
        const int nd = l0 + 8;
        float acc[8], win[15], kreg[8], u0[8];

        #pragma unroll
        for (int j = 0; j < 15; ++j) {
            const int li = l0 - 7 + j;
            win[j] = (li >= 0) ? Ub[li * SSM_H] : 0.f;   // win[j] = u[l0-7+j]
        }
        #pragma unroll
        for (int i = 0; i < 8; ++i) { acc[i] = 0.f; u0[i] = win[7 + i]; }
        #pragma unroll
        for (int j = 0; j < 8; ++j) kreg[j] = Kk[j * SSM_H + h];

        for (int d0 = 0; d0 < nd; d0 += 8) {
            float kn[8], nw[8];
            const int dn = d0 + 8;
            #pragma unroll
            for (int j = 0; j < 8; ++j)
                kn[j] = (dn + j < nd) ? Kk[(dn + j) * SSM_H + h] : 0.f;
            #pragma unroll
            for (int j = 0; j < 8; ++j) {
                const int li = l0 - d0 - 15 + j;
                nw[j] = (li >= 0) ? Ub[li * SSM_H] : 0.f;
            }
            // acc[i] += K[d0+dd] * u[l0+i-d0-dd]; win[j] = u[(l0-d0)-7+j]
            #pragma unroll
            for (int dd = 0; dd < 8; ++dd) {
                const float kv = kreg[dd];
                #pragma unroll
                for (int i = 0; i < 8; ++i)
                    acc[i] += kv * win[7 + i - dd];
            }
            #pragma unroll
            for (int j = 14; j >= 8; --j) win[j] = win[j - 8];
            #pragma unroll
            for (int j = 0; j < 8; ++j) { win[j] = nw[j]; kreg[j] = kn[j]; }
        }
        #pragma unroll
        for (int i = 0; i < 8; ++i)
            Yb[(l0 + i) * SSM_H] = acc[i] + dh * u0[i];
    }
}

extern "C" void kernel_launch(void* const* d_in, const int* in_sizes, int n_in,
                              void* d_out, int out_size, void* d_ws, size_t ws_size,
                              hipStream_t stream)
{
    const float* inp    = (const float*)d_in[0];  // (B,L,H)
    const float* As     = (const float*)d_in[1];  // (H,N,N)
    const float* Bsin   = (const float*)d_in[2];  // (H,N,1)
    const float* Csin   = (const float*)d_in[3];  // (H,1,N)
    const float* Dsin   = (const float*)d_in[4];  // (H,)
    const float* lsteps = (const float*)d_in[5];  // (H,)
    float* Y    = (float*)d_out;                  // (B,L,H)
    float* Kbuf = (float*)d_ws;                   // (L,H) = 1 MB scratch

    ssm_prep_kernel<<<dim3(SSM_H), dim3(256), 0, stream>>>(As, Bsin, Csin, lsteps, Kbuf);
    ssm_conv_kernel<<<dim3(SSM_B * 16 * 4), dim3(256), 0, stream>>>(inp, Kbuf, Dsin, Y);
}

// Round 3
// 197.157 us; speedup vs baseline: 1.2047x; 1.2047x over previous
//
#include <hip/hip_runtime.h>
#include <cstddef>

#define SSM_N 64
#define SSM_H 256
#define SSM_B 8
#define SSM_L 1024
#define PADM  68    // row stride (floats) for 64x64 LDS matrices; 272B rows, 16B-aligned
#define PADC  68    // row stride for 32-row chain buffers (float4-aligned)
#define KTP   1040  // K_T row stride in floats (padded; 4160B, 16B-aligned)

// One block per channel h. 256 threads = 4 waves; wave q owns output columns [16q,16q+16).
// Writes K transposed: KT[h*KTP + l]  (coalesced 4KB stream per block).
__global__ __launch_bounds__(256) void ssm_prep_kernel(
    const float* __restrict__ As, const float* __restrict__ Bsin,
    const float* __restrict__ Csin, const float* __restrict__ logsteps,
    float* __restrict__ KTout)
{
    __shared__ __align__(16) float B0[SSM_N * PADM];
    __shared__ __align__(16) float B1[SSM_N * PADM];
    __shared__ __align__(16) float CallL[32 * PADC];
    __shared__ __align__(16) float XallL[32 * PADC];
    __shared__ float pbuf[4 * 64];

    const int h    = blockIdx.x;
    const int tid  = threadIdx.x;
    const int lane = tid & 63;
    const int q    = tid >> 6;
    const int j0   = q * 16;

    const float step = expf(logsteps[h]);
    const float s    = 0.5f * step;

    // ---- 1. M = s*A: lane's row into 64 regs (all waves), staged in B1 (wave 0) ----
    float arow[64];
    {
        const float4* Ar = reinterpret_cast<const float4*>(As + (size_t)h * 4096 + lane * 64);
        #pragma unroll
        for (int r = 0; r < 16; ++r) {
            float4 v = Ar[r];
            arow[4*r+0] = s * v.x; arow[4*r+1] = s * v.y;
            arow[4*r+2] = s * v.z; arow[4*r+3] = s * v.w;
        }
        if (q == 0) {
            float4* wp = reinterpret_cast<float4*>(B1 + lane * PADM);
            #pragma unroll
            for (int r = 0; r < 16; ++r)
                wp[r] = make_float4(arow[4*r], arow[4*r+1], arow[4*r+2], arow[4*r+3]);
        }
    }
    __syncthreads();

    // ---- 2. Neumann Horner: B0 = M*M + M; then B0 = M*B0 + M  (B0 = S = M+M^2+M^3) ----
    #pragma unroll 1
    for (int it = 0; it < 2; ++it) {
        const float* Bop = (it == 0) ? B1 : B0;
        float acc[16];
        #pragma unroll
        for (int jj = 0; jj < 16; ++jj) acc[jj] = arow[j0 + jj];   // the "+M" term
        #pragma unroll
        for (int k = 0; k < 64; ++k) {
            const float a = arow[k];
            const float4* bp = reinterpret_cast<const float4*>(Bop + k * PADM + j0);
            const float4 b0 = bp[0], b1v = bp[1], b2 = bp[2], b3 = bp[3];
            acc[0]  += a * b0.x;  acc[1]  += a * b0.y;  acc[2]  += a * b0.z;  acc[3]  += a * b0.w;
            acc[4]  += a * b1v.x; acc[5]  += a * b1v.y; acc[6]  += a * b1v.z; acc[7]  += a * b1v.w;
            acc[8]  += a * b2.x;  acc[9]  += a * b2.y;  acc[10] += a * b2.z;  acc[11] += a * b2.w;
            acc[12] += a * b3.x;  acc[13] += a * b3.y;  acc[14] += a * b3.z;  acc[15] += a * b3.w;
        }
        float4* wp = reinterpret_cast<float4*>(B0 + lane * PADM + j0);
        wp[0] = make_float4(acc[0],  acc[1],  acc[2],  acc[3]);
        wp[1] = make_float4(acc[4],  acc[5],  acc[6],  acc[7]);
        wp[2] = make_float4(acc[8],  acc[9],  acc[10], acc[11]);
        wp[3] = make_float4(acc[12], acc[13], acc[14], acc[15]);
    }
    __syncthreads();

    // ---- 3. stage b, Cs; build AbT = I + 2*S^T into B1 ----
    if (q == 0)      pbuf[lane]  = Bsin[h * SSM_N + lane];
    else if (q == 1) CallL[lane] = Csin[h * SSM_N + lane];
    #pragma unroll
    for (int r = 0; r < 16; ++r) {
        int e = r * 256 + tid, i = e >> 6, j = e & 63;
        B1[j * PADM + i] = 2.f * B0[i * PADM + j] + ((i == j) ? 1.f : 0.f);
    }
    __syncthreads();

    // ---- 4. Bb = step*(b + S b) -> XallL row 0 (wave 0) ----
    if (q == 0) {
        float accb = 0.f;
        #pragma unroll
        for (int r = 0; r < 16; ++r) {
            const float4 sv = *reinterpret_cast<const float4*>(B0 + lane * PADM + 4 * r);
            accb += sv.x * pbuf[4*r] + sv.y * pbuf[4*r+1] + sv.z * pbuf[4*r+2] + sv.w * pbuf[4*r+3];
        }
        XallL[lane] = step * (pbuf[lane] + accb);
    }

    // ---- 5. c-chain: c_{j+1}[i] = sum_k c_j[k] * AbT[i][k] ----
    #pragma unroll 1
    for (int j = 0; j < 31; ++j) {
        const float* crow = CallL + j * PADC;
        float pp = 0.f;
        #pragma unroll
        for (int r = 0; r < 4; ++r) {
            const float4 cc = *reinterpret_cast<const float4*>(crow + j0 + 4 * r);
            const float4 aa = *reinterpret_cast<const float4*>(B1 + lane * PADM + j0 + 4 * r);
            pp += cc.x * aa.x + cc.y * aa.y + cc.z * aa.z + cc.w * aa.w;
        }
        pbuf[q * 64 + lane] = pp;
        __syncthreads();
        if (q == 0)
            CallL[(j + 1) * PADC + lane] =
                pbuf[lane] + pbuf[64 + lane] + pbuf[128 + lane] + pbuf[192 + lane];
        __syncthreads();
    }

    // ---- 6. five squarings of AbT: B1 -> B0 -> ... -> PT ends in B0 ----
    {
        float* src = B1;
        float* dst = B0;
        #pragma unroll 1
        for (int it = 0; it < 5; ++it) {
            #pragma unroll
            for (int r = 0; r < 16; ++r) {
                const float4 v = *reinterpret_cast<const float4*>(src + lane * PADM + 4 * r);
                arow[4*r] = v.x; arow[4*r+1] = v.y; arow[4*r+2] = v.z; arow[4*r+3] = v.w;
            }
            float acc[16];
            #pragma unroll
            for (int jj = 0; jj < 16; ++jj) acc[jj] = 0.f;
            #pragma unroll
            for (int k = 0; k < 64; ++k) {
                const float a = arow[k];
                const float4* bp = reinterpret_cast<const float4*>(src + k * PADM + j0);
                const float4 b0 = bp[0], b1v = bp[1], b2 = bp[2], b3 = bp[3];
                acc[0]  += a * b0.x;  acc[1]  += a * b0.y;  acc[2]  += a * b0.z;  acc[3]  += a * b0.w;
                acc[4]  += a * b1v.x; acc[5]  += a * b1v.y; acc[6]  += a * b1v.z; acc[7]  += a * b1v.w;
                acc[8]  += a * b2.x;  acc[9]  += a * b2.y;  acc[10] += a * b2.z;  acc[11] += a * b2.w;
                acc[12] += a * b3.x;  acc[13] += a * b3.y;  acc[14] += a * b3.z;  acc[15] += a * b3.w;
            }
            float4* wp = reinterpret_cast<float4*>(dst + lane * PADM + j0);
            wp[0] = make_float4(acc[0],  acc[1],  acc[2],  acc[3]);
            wp[1] = make_float4(acc[4],  acc[5],  acc[6],  acc[7]);
            wp[2] = make_float4(acc[8],  acc[9],  acc[10], acc[11]);
            wp[3] = make_float4(acc[12], acc[13], acc[14], acc[15]);
            __syncthreads();
            float* tmp = src; src = dst; dst = tmp;
        }
    }

    // ---- 7. P := PT^T into B1 ----
    #pragma unroll
    for (int r = 0; r < 16; ++r) {
        int e = r * 256 + tid, i = e >> 6, jj = e & 63;
        B1[i * PADM + jj] = B0[jj * PADM + i];
    }
    __syncthreads();

    // ---- 8. x-chain: x_{m+1}[i] = sum_k P[i][k] x_m[k] ----
    #pragma unroll 1
    for (int m = 0; m < 31; ++m) {
        const float* xrow = XallL + m * PADC;
        float pp = 0.f;
        #pragma unroll
        for (int r = 0; r < 4; ++r) {
            const float4 xx = *reinterpret_cast<const float4*>(xrow + j0 + 4 * r);
            const float4 aa = *reinterpret_cast<const float4*>(B1 + lane * PADM + j0 + 4 * r);
            pp += xx.x * aa.x + xx.y * aa.y + xx.z * aa.z + xx.w * aa.w;
        }
        pbuf[q * 64 + lane] = pp;
        __syncthreads();
        if (q == 0)
            XallL[(m + 1) * PADC + lane] =
                pbuf[lane] + pbuf[64 + lane] + pbuf[128 + lane] + pbuf[192 + lane];
        __syncthreads();
    }

    // ---- 9. KT[h][32m + j] = dot(c_j, x_m)  -- coalesced contiguous write ----
    #pragma unroll
    for (int r = 0; r < 4; ++r) {
        int l = r * 256 + tid, mm = l >> 5, jj = l & 31;
        const float4* cr = reinterpret_cast<const float4*>(CallL + jj * PADC);
        const float4* xr = reinterpret_cast<const float4*>(XallL + mm * PADC);
        float sacc = 0.f;
        #pragma unroll
        for (int i = 0; i < 16; ++i) {
            const float4 c4 = cr[i], x4 = xr[i];
            sacc += c4.x * x4.x + c4.y * x4.y + c4.z * x4.z + c4.w * x4.w;
        }
        KTout[(size_t)h * KTP + l] = sacc;
    }
}

// KT (H x KTP, padded) -> K (L x H). 32x32 LDS tiles, coalesced both sides.
__global__ __launch_bounds__(256) void ssm_ktr_kernel(
    const float* __restrict__ KT, float* __restrict__ K)
{
    __shared__ float tile[32][33];
    const int l0 = (blockIdx.x & 31) * 32;
    const int h0 = (blockIdx.x >> 5) * 32;
    const int c  = threadIdx.x & 31;
    const int r0 = threadIdx.x >> 5;
    #pragma unroll
    for (int k = 0; k < 4; ++k)
        tile[r0 + 8 * k][c] = KT[(size_t)(h0 + r0 + 8 * k) * KTP + l0 + c];
    __syncthreads();
    #pragma unroll
    for (int k = 0; k < 4; ++k)
        K[(size_t)(l0 + r0 + 8 * k) * SSM_H + h0 + c] = tile[c][r0 + 8 * k];
}

// Causal conv: y[b,l,h] = sum_d K[d,h]*u[b,l-d,h] + Ds[h]*u[b,l,h].
// thread = h (coalesced). Block = (b, pair p): tiles p and 127-p of 8 rows each
// -> uniform 129 chunks of 8 d-steps, NO bounds checks in steady-state chunks.
__global__ __launch_bounds__(256) void ssm_conv_kernel(
    const float* __restrict__ U, const float* __restrict__ Kk,
    const float* __restrict__ Ds, float* __restrict__ Y)
{
    const int h = threadIdx.x;
    const int b = blockIdx.x & 7;
    const int p = blockIdx.x >> 3;
    const float dh = Ds[h];
    const float* Ub = U + (size_t)b * SSM_L * SSM_H + h;
    float* Yb = Y + (size_t)b * SSM_L * SSM_H + h;

    #pragma unroll
    for (int half = 0; half < 2; ++half) {
        const int t  = (half == 0) ? p : (127 - p);
        const int l0 = t << 3;
        float acc[8], win[15], kreg[8], u0[8];

        // window: win[j] = u[l0-7+j], zeros below 0 (only possible at t=0)
        #pragma unroll
        for (int j = 0; j < 15; ++j) {
            const int li = l0 - 7 + j;
            win[j] = (li >= 0) ? Ub[li * SSM_H] : 0.f;
        }
        #pragma unroll
        for (int i = 0; i < 8; ++i) { acc[i] = 0.f; u0[i] = win[7 + i]; }
        #pragma unroll
        for (int j = 0; j < 8; ++j) kreg[j] = Kk[j * SSM_H + h];   // d=0..7, nd>=8 always

        // clean chunks c = 0..t-2: both prefetches provably in range, no guards
        const float* kp = Kk + 8 * SSM_H + h;          // K[8c+8+j] base
        const float* up = Ub + (l0 - 15) * SSM_H;      // u[l0-8c-15+j] base
        #pragma unroll 2
        for (int c = 0; c < t - 1; ++c) {
            float kn[8], nw[8];
            #pragma unroll
            for (int j = 0; j < 8; ++j) kn[j] = kp[j * SSM_H];
            #pragma unroll
            for (int j = 0; j < 8; ++j) nw[j] = up[j * SSM_H];
            #pragma unroll
            for (int dd = 0; dd < 8; ++dd) {
                const float kv = kreg[dd];
                #pragma unroll
                for (int i = 0; i < 8; ++i) acc[i] += kv * win[7 + i - dd];
            }
            #pragma unroll
            for (int j = 14; j >= 8; --j) win[j] = win[j - 8];
            #pragma unroll
            for (int j = 0; j < 8; ++j) { win[j] = nw[j]; kreg[j] = kn[j]; }
            kp += 8 * SSM_H;
            up -= 8 * SSM_H;
        }

        // chunk c = t-1 (exists when t>=1): u-prefetch is all zeros except u[0]
        if (t >= 1) {
            float kn[8];
            #pragma unroll
            for (int j = 0; j < 8; ++j) kn[j] = Kk[(8 * t + j) * SSM_H + h];
            const float uz = Ub[0];
            #pragma unroll
            for (int dd = 0; dd < 8; ++dd) {
                const float kv = kreg[dd];
                #pragma unroll
                for (int i = 0; i < 8; ++i) acc[i] += kv * win[7 + i - dd];
            }
            #pragma unroll
            for (int j = 14; j >= 8; --j) win[j] = win[j - 8];
            #pragma unroll
            for (int j = 0; j < 7; ++j) win[j] = 0.f;
            win[7] = uz;
            #pragma unroll
            for (int j = 0; j < 8; ++j) kreg[j] = kn[j];
        }

        // final chunk c = t: FMA only
        #pragma unroll
        for (int dd = 0; dd < 8; ++dd) {
            const float kv = kreg[dd];
            #pragma unroll
            for (int i = 0; i < 8; ++i) acc[i] += kv * win[7 + i - dd];
        }

        #pragma unroll
        for (int i = 0; i < 8; ++i)
            Yb[(l0 + i) * SSM_H] = acc[i] + dh * u0[i];
    }
}

extern "C" void kernel_launch(void* const* d_in, const int* in_sizes, int n_in,
                              void* d_out, int out_size, void* d_ws, size_t ws_size,
                              hipStream_t stream)
{
    const float* inp    = (const float*)d_in[0];  // (B,L,H)
    const float* As     = (const float*)d_in[1];  // (H,N,N)
    const float* Bsin   = (const float*)d_in[2];  // (H,N,1)
    const float* Csin   = (const float*)d_in[3];  // (H,1,N)
    const float* Dsin   = (const float*)d_in[4];  // (H,)
    const float* lsteps = (const float*)d_in[5];  // (H,)
    float* Y    = (float*)d_out;                  // (B,L,H)
    // KT staged in d_out's first 1.07MB (conv overwrites all of d_out with Y,
    // and conv never reads d_out). K (L,H) in the proven-size 1MB d_ws.
    float* KT   = (float*)d_out;
    float* Kbuf = (float*)d_ws;

    ssm_prep_kernel<<<dim3(SSM_H), dim3(256), 0, stream>>>(As, Bsin, Csin, lsteps, KT);
    ssm_ktr_kernel<<<dim3(256), dim3(256), 0, stream>>>(KT, Kbuf);
    ssm_conv_kernel<<<dim3(SSM_B * 64), dim3(256), 0, stream>>>(inp, Kbuf, Dsin, Y);
}